// Round 2
// baseline (563.979 us; speedup 1.0000x reference)
//
#include <hip/hip_runtime.h>

// ---------------- problem constants ----------------
#define NTOK 64      // tokens per window
#define CDIM 256     // channels
#define NHEAD 8
#define HD 32        // head dim
#define NWIN 64      // windows per image (mask dim 0)

typedef __attribute__((ext_vector_type(8))) short v8s;   // 8 x bf16 raw bits (4 VGPRs)
typedef __attribute__((ext_vector_type(4))) short v4s;
typedef __attribute__((ext_vector_type(4))) float v4f;

#define CFENCE() asm volatile("" ::: "memory")

// ---------------- workspace layout (bytes) ----------------
#define WQT_OFF   0u         // WqT  bf16 [256][256]  (out-major, contiguous in k)
#define WKVT_OFF  131072u    // WkvT bf16 [512][256]
#define WPT_OFF   393216u    // WpT  bf16 [256][256]
#define ITB_OFF   524288u    // float2 [8][64][64] = {inv_tau, cpb_bias}
#define WS_BYTES  786432u

static __device__ __forceinline__ short f2bf(float f) {
  union { float f; unsigned int u; } v; v.f = f;
  unsigned int u = v.u;
  return (short)((u + 0x7fffu + ((u >> 16) & 1u)) >> 16);   // RNE
}

// ---------------- prep: weight transpose+cast, inv_tau ----------------
__global__ void prep_kernel(const float* __restrict__ Wq, const float* __restrict__ Wkv,
                            const float* __restrict__ Wp, const float* __restrict__ tau,
                            short* __restrict__ WqT, short* __restrict__ WkvT,
                            short* __restrict__ WpT, float2* __restrict__ itb) {
  int id = blockIdx.x * 256 + threadIdx.x;
  if (id < 65536) {                       // WqT[o][i] = Wq[i][o]
    int o = id >> 8, i = id & 255;
    WqT[id] = f2bf(Wq[i * 256 + o]);
  } else if (id < 196608) {               // WkvT[o][i] = Wkv[i][o]
    int t = id - 65536; int o = t >> 8, i = t & 255;
    WkvT[t] = f2bf(Wkv[i * 512 + o]);
  } else if (id < 262144) {               // WpT[o][i] = Wp[i][o]
    int t = id - 196608; int o = t >> 8, i = t & 255;
    WpT[t] = f2bf(Wp[i * 256 + o]);
  } else if (id < 294912) {               // inv_tau
    int t = id - 262144;
    itb[t].x = 1.0f / fmaxf(tau[t], 0.01f);
  }
}

// ---------------- prep: continuous relative position bias MLP ----------------
__global__ void cpb_kernel(const float* __restrict__ w1, const float* __restrict__ b1,
                           const float* __restrict__ w2, const float* __restrict__ b2,
                           const float* __restrict__ lri, float2* __restrict__ itb) {
  int ij = blockIdx.x * 256 + threadIdx.x;     // 0..4095 = i*64+j
  float l0 = lri[ij * 2], l1 = lri[ij * 2 + 1];
  float acc[8];
#pragma unroll
  for (int h = 0; h < 8; ++h) acc[h] = b2[h];
  for (int c = 0; c < 256; ++c) {
    float hv = fmaxf(l0 * w1[c] + l1 * w1[256 + c] + b1[c], 0.0f);
#pragma unroll
    for (int h = 0; h < 8; ++h) acc[h] += hv * w2[c * 8 + h];
  }
#pragma unroll
  for (int h = 0; h < 8; ++h) itb[h * 4096 + ij].y = acc[h];
}

// ---------------- fused GEMM helper: 64 tokens x 32 out-cols, K=256 ----------------
// A from LDS [64][264] bf16 (token-major), B from global bf16 [n][256] (k-contiguous).
static __device__ __forceinline__ void gemm_64x32_k256(
    const short* aLds, const short* Bg, int qd, int cc, v4f acc[4][2]) {
#pragma unroll
  for (int it = 0; it < 8; ++it) {
    const int k0 = it * 32;
    v8s b0 = *(const v8s*)(Bg + cc * 256 + k0 + qd * 8);
    v8s b1 = *(const v8s*)(Bg + (16 + cc) * 256 + k0 + qd * 8);
#pragma unroll
    for (int mt = 0; mt < 4; ++mt) {
      v8s a = *(const v8s*)(aLds + (mt * 16 + cc) * 264 + k0 + qd * 8);
      acc[mt][0] = __builtin_amdgcn_mfma_f32_16x16x32_bf16(a, b0, acc[mt][0], 0, 0, 0);
      acc[mt][1] = __builtin_amdgcn_mfma_f32_16x16x32_bf16(a, b1, acc[mt][1], 0, 0, 0);
    }
  }
}

// ---------------- main fused kernel: one block = one window, wave w = head w ----------------
// LDS (shorts): regA @0     : xs[64][264] -> per-wave q̂/P tiles [64][40] -> os[64][264]
//               regB @20480 : kvs[64][264] -> per-wave { k̂[64][40], vT[32][72] }
__global__ __launch_bounds__(512, 2) void wattn_kernel(
    const float* __restrict__ x, const float* __restrict__ KV,
    const float* __restrict__ mask,
    const float* __restrict__ bq, const float* __restrict__ bkv,
    const float* __restrict__ bp,
    const short* __restrict__ WqT, const short* __restrict__ WkvT,
    const short* __restrict__ WpT, const float2* __restrict__ itb,
    float* __restrict__ out) {
  __shared__ short sm[59392];     // 118784 B

  const int b = blockIdx.x;
  const int tid = threadIdx.x;
  const int w = tid >> 6;         // wave index == head index
  const int lane = tid & 63;
  const int qd = lane >> 4;       // quad (lane>>4)
  const int cc = lane & 15;       // col-in-tile (lane&15)
  const v4f vzero = {0.f, 0.f, 0.f, 0.f};

  // ---- phase 0: stage x, KV -> bf16 LDS [64][264] ----
  {
    const float4* xb = (const float4*)(x + (size_t)b * 16384);
    const float4* kb = (const float4*)(KV + (size_t)b * 16384);
    for (int i = tid; i < 4096; i += 512) {
      int r = i >> 6, col = (i & 63) << 2;
      float4 vx = xb[i];
      float4 vk = kb[i];
      v4s px, pk;
      px[0] = f2bf(vx.x); px[1] = f2bf(vx.y); px[2] = f2bf(vx.z); px[3] = f2bf(vx.w);
      pk[0] = f2bf(vk.x); pk[1] = f2bf(vk.y); pk[2] = f2bf(vk.z); pk[3] = f2bf(vk.w);
      *(v4s*)&sm[r * 264 + col] = px;
      *(v4s*)&sm[20480 + r * 264 + col] = pk;
    }
  }
  __syncthreads();

  // ---- phase 1: q = x @ Wq[:, 32w..32w+32) + bq ; per-head row-normalize ----
  v4f qa[4][2];
#pragma unroll
  for (int mt = 0; mt < 4; ++mt) { qa[mt][0] = vzero; qa[mt][1] = vzero; }
  gemm_64x32_k256(sm, WqT + (32 * w) * 256, qd, cc, qa);
  {
    float b0 = bq[32 * w + cc], b1 = bq[32 * w + 16 + cc];
#pragma unroll
    for (int mt = 0; mt < 4; ++mt)
#pragma unroll
      for (int rg = 0; rg < 4; ++rg) {
        float a0 = qa[mt][0][rg] + b0;
        float a1 = qa[mt][1][rg] + b1;
        // per-head row norm: quad's 16 lanes hold this row's 32 dims (2/lane)
        float s = a0 * a0 + a1 * a1;
        s += __shfl_xor(s, 1); s += __shfl_xor(s, 2);
        s += __shfl_xor(s, 4); s += __shfl_xor(s, 8);
        float inv = rsqrtf(s + 1e-24f);
        qa[mt][0][rg] = a0 * inv;
        qa[mt][1][rg] = a1 * inv;
      }
  }
  __syncthreads();   // all xs reads done -> regA reusable

  // write normalized q̂ tile (per-wave, [64][40] bf16) into regA
  short* qt = sm + w * 2560;
#pragma unroll
  for (int mt = 0; mt < 4; ++mt)
#pragma unroll
    for (int rg = 0; rg < 4; ++rg) {
      int row = mt * 16 + qd * 4 + rg;
      qt[row * 40 + cc] = f2bf(qa[mt][0][rg]);
      qt[row * 40 + 16 + cc] = f2bf(qa[mt][1][rg]);
    }

  // ---- phase 2/3: k, v = KV @ Wkv slices + bkv ----
  v4f ka[4][2], va[4][2];
#pragma unroll
  for (int mt = 0; mt < 4; ++mt) { ka[mt][0] = vzero; ka[mt][1] = vzero; va[mt][0] = vzero; va[mt][1] = vzero; }
  gemm_64x32_k256(sm + 20480, WkvT + (32 * w) * 256, qd, cc, ka);
  {
    float b0 = bkv[32 * w + cc], b1 = bkv[32 * w + 16 + cc];
#pragma unroll
    for (int mt = 0; mt < 4; ++mt)
#pragma unroll
      for (int rg = 0; rg < 4; ++rg) {
        float a0 = ka[mt][0][rg] + b0;
        float a1 = ka[mt][1][rg] + b1;
        float s = a0 * a0 + a1 * a1;
        s += __shfl_xor(s, 1); s += __shfl_xor(s, 2);
        s += __shfl_xor(s, 4); s += __shfl_xor(s, 8);
        float inv = rsqrtf(s + 1e-24f);
        ka[mt][0][rg] = a0 * inv;
        ka[mt][1][rg] = a1 * inv;
      }
  }
  gemm_64x32_k256(sm + 20480, WkvT + (256 + 32 * w) * 256, qd, cc, va);
  {
    float b0 = bkv[256 + 32 * w + cc], b1 = bkv[256 + 32 * w + 16 + cc];
#pragma unroll
    for (int mt = 0; mt < 4; ++mt)
#pragma unroll
      for (int rg = 0; rg < 4; ++rg) { va[mt][0][rg] += b0; va[mt][1][rg] += b1; }
  }
  __syncthreads();   // all kvs reads done -> regB reusable

  // write k̂ [64][40] and vT [32][72] tiles (per-wave) into regB
  short* kt = sm + 20480 + w * 4864;
  short* vt = kt + 2560;
#pragma unroll
  for (int mt = 0; mt < 4; ++mt)
#pragma unroll
    for (int rg = 0; rg < 4; ++rg) {
      int row = mt * 16 + qd * 4 + rg;        // token
      kt[row * 40 + cc] = f2bf(ka[mt][0][rg]);
      kt[row * 40 + 16 + cc] = f2bf(ka[mt][1][rg]);
      vt[cc * 72 + row] = f2bf(va[mt][0][rg]);        // vT[dim][token]
      vt[(16 + cc) * 72 + row] = f2bf(va[mt][1][rg]);
    }
  CFENCE();

  // ---- phase 4: attention (entirely wave-local, head h = w) ----
  // S = q̂ k̂ᵀ  (M=64,N=64,K=32 -> 16 MFMAs)
  v8s aq[4];
#pragma unroll
  for (int mt = 0; mt < 4; ++mt)
    aq[mt] = *(const v8s*)(qt + (mt * 16 + cc) * 40 + qd * 8);
  v4f S[4][4];
#pragma unroll
  for (int nt = 0; nt < 4; ++nt) {
    v8s bk = *(const v8s*)(kt + (nt * 16 + cc) * 40 + qd * 8);
#pragma unroll
    for (int mt = 0; mt < 4; ++mt)
      S[mt][nt] = __builtin_amdgcn_mfma_f32_16x16x32_bf16(aq[mt], bk, vzero, 0, 0, 0);
  }

  // scale by 1/tau, add cpb bias + mask, row softmax (rows live in one quad)
  {
    const float2* itbh = itb + w * 4096;
    const float* mw = mask + (size_t)(b & (NWIN - 1)) * 4096;
#pragma unroll
    for (int mt = 0; mt < 4; ++mt)
#pragma unroll
      for (int rg = 0; rg < 4; ++rg) {
        int i = mt * 16 + qd * 4 + rg;
        float vals[4];
#pragma unroll
        for (int nt = 0; nt < 4; ++nt) {
          int j = nt * 16 + cc;
          float2 tb = itbh[i * 64 + j];
          vals[nt] = S[mt][nt][rg] * tb.x + tb.y + mw[i * 64 + j];
        }
        float mx = fmaxf(fmaxf(vals[0], vals[1]), fmaxf(vals[2], vals[3]));
        mx = fmaxf(mx, __shfl_xor(mx, 1)); mx = fmaxf(mx, __shfl_xor(mx, 2));
        mx = fmaxf(mx, __shfl_xor(mx, 4)); mx = fmaxf(mx, __shfl_xor(mx, 8));
        float sum = 0.f;
#pragma unroll
        for (int nt = 0; nt < 4; ++nt) {
          float e = __expf(vals[nt] - mx);
          S[mt][nt][rg] = e;
          sum += e;
        }
        sum += __shfl_xor(sum, 1); sum += __shfl_xor(sum, 2);
        sum += __shfl_xor(sum, 4); sum += __shfl_xor(sum, 8);
        float rs = 1.0f / sum;
#pragma unroll
        for (int nt = 0; nt < 4; ++nt) S[mt][nt][rg] *= rs;
      }
  }

  // out_h = P @ v_h  (M=64,N=32,K=64; K chunked by 32 through per-wave P tile)
  v4f o[4][2];
#pragma unroll
  for (int mt = 0; mt < 4; ++mt) { o[mt][0] = vzero; o[mt][1] = vzero; }
  short* pt = qt;   // reuse q̂ tile slot (q̂ fully consumed)
#pragma unroll
  for (int kc = 0; kc < 2; ++kc) {
    CFENCE();
#pragma unroll
    for (int mt = 0; mt < 4; ++mt)
#pragma unroll
      for (int rg = 0; rg < 4; ++rg) {
        int row = mt * 16 + qd * 4 + rg;
        pt[row * 40 + cc] = f2bf(S[mt][kc * 2][rg]);
        pt[row * 40 + 16 + cc] = f2bf(S[mt][kc * 2 + 1][rg]);
      }
    CFENCE();   // same-wave DS ops are in-order; fence stops compiler reordering
#pragma unroll
    for (int mt = 0; mt < 4; ++mt) {
      v8s ap = *(const v8s*)(pt + (mt * 16 + cc) * 40 + qd * 8);
#pragma unroll
      for (int d = 0; d < 2; ++d) {
        v8s bv = *(const v8s*)(vt + (d * 16 + cc) * 72 + kc * 32 + qd * 8);
        o[mt][d] = __builtin_amdgcn_mfma_f32_16x16x32_bf16(ap, bv, o[mt][d], 0, 0, 0);
      }
    }
  }

  // ---- phase 5: gather heads into os[64][264] (regA), then out = os @ Wp + bp ----
  __syncthreads();   // all waves done reading their P/v tiles
#pragma unroll
  for (int mt = 0; mt < 4; ++mt)
#pragma unroll
    for (int rg = 0; rg < 4; ++rg) {
      int row = mt * 16 + qd * 4 + rg;
      sm[row * 264 + 32 * w + cc] = f2bf(o[mt][0][rg]);
      sm[row * 264 + 32 * w + 16 + cc] = f2bf(o[mt][1][rg]);
    }
  __syncthreads();

  v4f pa[4][2];
#pragma unroll
  for (int mt = 0; mt < 4; ++mt) { pa[mt][0] = vzero; pa[mt][1] = vzero; }
  gemm_64x32_k256(sm, WpT + (32 * w) * 256, qd, cc, pa);
  {
    float b0 = bp[32 * w + cc], b1 = bp[32 * w + 16 + cc];
    float* ob = out + (size_t)b * 16384;
#pragma unroll
    for (int mt = 0; mt < 4; ++mt)
#pragma unroll
      for (int rg = 0; rg < 4; ++rg) {
        int row = mt * 16 + qd * 4 + rg;
        ob[row * 256 + 32 * w + cc] = pa[mt][0][rg] + b0;
        ob[row * 256 + 32 * w + 16 + cc] = pa[mt][1][rg] + b1;
      }
  }
}

// ---------------- launch ----------------
extern "C" void kernel_launch(void* const* d_in, const int* in_sizes, int n_in,
                              void* d_out, int out_size, void* d_ws, size_t ws_size,
                              hipStream_t stream) {
  const float* x    = (const float*)d_in[0];
  const float* KV   = (const float*)d_in[1];
  const float* mask = (const float*)d_in[2];
  const float* Wq   = (const float*)d_in[3];
  const float* bq   = (const float*)d_in[4];
  const float* Wkv  = (const float*)d_in[5];
  const float* bkv  = (const float*)d_in[6];
  const float* Wp   = (const float*)d_in[7];
  const float* bp   = (const float*)d_in[8];
  const float* cw1  = (const float*)d_in[9];
  const float* cb1  = (const float*)d_in[10];
  const float* cw2  = (const float*)d_in[11];
  const float* cb2  = (const float*)d_in[12];
  const float* tau  = (const float*)d_in[13];
  const float* lri  = (const float*)d_in[14];

  unsigned char* ws = (unsigned char*)d_ws;
  short* WqT   = (short*)(ws + WQT_OFF);
  short* WkvT  = (short*)(ws + WKVT_OFF);
  short* WpT   = (short*)(ws + WPT_OFF);
  float2* itb  = (float2*)(ws + ITB_OFF);

  prep_kernel<<<1152, 256, 0, stream>>>(Wq, Wkv, Wp, tau, WqT, WkvT, WpT, itb);
  cpb_kernel<<<16, 256, 0, stream>>>(cw1, cb1, cw2, cb2, lri, itb);
  wattn_kernel<<<2048, 512, 0, stream>>>(x, KV, mask, bq, bkv, bp,
                                         WqT, WkvT, WpT, itb, (float*)d_out);
}

// Round 3
// 559.040 us; speedup vs baseline: 1.0088x; 1.0088x over previous
//
#include <hip/hip_runtime.h>
#include <hip/hip_bf16.h>

// ---------------- problem constants ----------------
#define NWIN 64      // windows per image (mask dim 0)

typedef __attribute__((ext_vector_type(8))) short v8s;   // 8 x bf16 raw bits (4 VGPRs)
typedef __attribute__((ext_vector_type(4))) float v4f;

// ---------------- workspace layout (bytes) ----------------
#define WQT_OFF   0u         // WqT  bf16 [256][256]  (out-major, contiguous in k)
#define WKVT_OFF  131072u    // WkvT bf16 [512][256]
#define WPT_OFF   393216u    // WpT  bf16 [256][256]
#define ITB_OFF   524288u    // float2 [8][64][64] = {inv_tau, cpb_bias}

static __device__ __forceinline__ short f2bf(float f) {
  union { float f; unsigned int u; } v; v.f = f;
  unsigned int u = v.u;
  return (short)((u + 0x7fffu + ((u >> 16) & 1u)) >> 16);   // RNE
}

// pack two fp32 -> one int holding (bf16(lo) | bf16(hi)<<16) via v_cvt_pk_bf16_f32
static __device__ __forceinline__ int packbf(float lo, float hi) {
  __hip_bfloat162 h = __float22bfloat162_rn(float2{lo, hi});
  union { __hip_bfloat162 h; int i; } u; u.h = h; return u.i;
}

// ---------------- prep: weight transpose+cast, inv_tau ----------------
__global__ void prep_kernel(const float* __restrict__ Wq, const float* __restrict__ Wkv,
                            const float* __restrict__ Wp, const float* __restrict__ tau,
                            short* __restrict__ WqT, short* __restrict__ WkvT,
                            short* __restrict__ WpT, float2* __restrict__ itb) {
  int id = blockIdx.x * 256 + threadIdx.x;
  if (id < 65536) {                       // WqT[o][i] = Wq[i][o]
    int o = id >> 8, i = id & 255;
    WqT[id] = f2bf(Wq[i * 256 + o]);
  } else if (id < 196608) {               // WkvT[o][i] = Wkv[i][o]
    int t = id - 65536; int o = t >> 8, i = t & 255;
    WkvT[t] = f2bf(Wkv[i * 512 + o]);
  } else if (id < 262144) {               // WpT[o][i] = Wp[i][o]
    int t = id - 196608; int o = t >> 8, i = t & 255;
    WpT[t] = f2bf(Wp[i * 256 + o]);
  } else if (id < 294912) {               // inv_tau
    int t = id - 262144;
    itb[t].x = 1.0f / fmaxf(tau[t], 0.01f);
  }
}

// ---------------- prep: continuous relative position bias MLP ----------------
__global__ void cpb_kernel(const float* __restrict__ w1, const float* __restrict__ b1,
                           const float* __restrict__ w2, const float* __restrict__ b2,
                           const float* __restrict__ lri, float2* __restrict__ itb) {
  int ij = blockIdx.x * 256 + threadIdx.x;     // 0..4095 = i*64+j
  float l0 = lri[ij * 2], l1 = lri[ij * 2 + 1];
  float acc[8];
#pragma unroll
  for (int h = 0; h < 8; ++h) acc[h] = b2[h];
  for (int c = 0; c < 256; ++c) {
    float hv = fmaxf(l0 * w1[c] + l1 * w1[256 + c] + b1[c], 0.0f);
#pragma unroll
    for (int h = 0; h < 8; ++h) acc[h] += hv * w2[c * 8 + h];
  }
#pragma unroll
  for (int h = 0; h < 8; ++h) itb[h * 4096 + ij].y = acc[h];
}

// ---------------- register transform: ᵀ-C-layout -> MFMA A/B fragment ----------------
// Source (per 16-wide tile): lane (cc,qd_s) holds pack u = (elem d=..+2u, d=..+2u+1),
// register-version p0* for tile-half 0, p1* for tile-half 1 (selected by qd>>1).
// Output: v8s fragment, word t from srcLane = cc + 32*(qd&1) + 16*(t>>1), u = t&1.
// (identity: md*16 + qd_s*4 + 2*(t&1) == 8*qd + 2*t)
static __device__ __forceinline__ v8s xform_tile(int p0a, int p0b, int p1a, int p1b,
                                                 int base, int mdsel) {
  int a0 = __shfl(p0a, base, 64),      b0 = __shfl(p1a, base, 64);
  int a1 = __shfl(p0b, base, 64),      b1 = __shfl(p1b, base, 64);
  int a2 = __shfl(p0a, base + 16, 64), b2 = __shfl(p1a, base + 16, 64);
  int a3 = __shfl(p0b, base + 16, 64), b3 = __shfl(p1b, base + 16, 64);
  union { v8s v; int i[4]; } r;
  r.i[0] = mdsel ? b0 : a0;
  r.i[1] = mdsel ? b1 : a1;
  r.i[2] = mdsel ? b2 : a2;
  r.i[3] = mdsel ? b3 : a3;
  return r.v;
}

// ---------------- main fused kernel: one block = one window, wave w = head w ----------------
// LDS: xs[64][264] bf16 @0 (reused for os), kvs[64][264] @16896.  Total 67584 B -> 2 blocks/CU.
__global__ __launch_bounds__(512, 4) void wattn_kernel(
    const float* __restrict__ x, const float* __restrict__ KV,
    const float* __restrict__ mask,
    const float* __restrict__ bq, const float* __restrict__ bkv,
    const float* __restrict__ bp,
    const short* __restrict__ WqT, const short* __restrict__ WkvT,
    const short* __restrict__ WpT, const float2* __restrict__ itb,
    float* __restrict__ out) {
  __shared__ short sm[33792];

  const int b = blockIdx.x;
  const int tid = threadIdx.x;
  const int w = tid >> 6;          // wave index == head index
  const int lane = tid & 63;
  const int cc = lane & 15;
  const int qd = lane >> 4;
  const int base = cc + 32 * (qd & 1);
  const int mdsel = qd >> 1;
  const v4f vzero = {0.f, 0.f, 0.f, 0.f};
  short* xs = sm;
  short* kvs = sm + 16896;

  // ---- phase 0: stage x, KV -> bf16 LDS [64][264] ----
  {
    const float4* xb = (const float4*)(x + (size_t)b * 16384);
    const float4* kb = (const float4*)(KV + (size_t)b * 16384);
#pragma unroll
    for (int ii = 0; ii < 8; ++ii) {
      int i = tid + ii * 512;
      int r = i >> 6, col = (i & 63) << 2;
      float4 vx = xb[i];
      float4 vk = kb[i];
      int2 px = { packbf(vx.x, vx.y), packbf(vx.z, vx.w) };
      int2 pk = { packbf(vk.x, vk.y), packbf(vk.z, vk.w) };
      *(int2*)&xs[r * 264 + col] = px;
      *(int2*)&kvs[r * 264 + col] = pk;
    }
  }
  __syncthreads();

  // ---- phase 1: q̂ᵀ = (Wq-slice)ᵀ x ᵀ (swapped operands) ----
  // Dq[md][nt]: lane holds q̂ᵀ[d = md*16+qd*4+rg][token = nt*16+cc]
  v4f Dq[2][4];
#pragma unroll
  for (int md = 0; md < 2; ++md)
#pragma unroll
    for (int nt = 0; nt < 4; ++nt) Dq[md][nt] = vzero;
  {
    const short* wqb = WqT + (32 * w + cc) * 256 + qd * 8;
#pragma unroll
    for (int it = 0; it < 8; ++it) {
      v8s a0 = *(const v8s*)(wqb + it * 32);
      v8s a1 = *(const v8s*)(wqb + 16 * 256 + it * 32);
#pragma unroll
      for (int nt = 0; nt < 4; ++nt) {
        v8s bx = *(const v8s*)(xs + (nt * 16 + cc) * 264 + it * 32 + qd * 8);
        Dq[0][nt] = __builtin_amdgcn_mfma_f32_16x16x32_bf16(a0, bx, Dq[0][nt], 0, 0, 0);
        Dq[1][nt] = __builtin_amdgcn_mfma_f32_16x16x32_bf16(a1, bx, Dq[1][nt], 0, 0, 0);
      }
    }
  }
  // bias + per-head row-normalize + pack + xform -> qB (B-frags for Sᵀ)
  v8s qB[4];
  {
    v4f b0 = *(const v4f*)(bq + 32 * w + qd * 4);
    v4f b1 = *(const v4f*)(bq + 32 * w + 16 + qd * 4);
#pragma unroll
    for (int nt = 0; nt < 4; ++nt) {
      float s = 0.f;
#pragma unroll
      for (int rg = 0; rg < 4; ++rg) {
        float v0 = Dq[0][nt][rg] + b0[rg];
        float v1 = Dq[1][nt][rg] + b1[rg];
        Dq[0][nt][rg] = v0; Dq[1][nt][rg] = v1;
        s += v0 * v0 + v1 * v1;
      }
      s += __shfl_xor(s, 16); s += __shfl_xor(s, 32);
      float inv = rsqrtf(s + 1e-24f);
      int p00 = packbf(Dq[0][nt][0] * inv, Dq[0][nt][1] * inv);
      int p01 = packbf(Dq[0][nt][2] * inv, Dq[0][nt][3] * inv);
      int p10 = packbf(Dq[1][nt][0] * inv, Dq[1][nt][1] * inv);
      int p11 = packbf(Dq[1][nt][2] * inv, Dq[1][nt][3] * inv);
      qB[nt] = xform_tile(p00, p01, p10, p11, base, mdsel);
    }
  }

  // ---- phase 2: merged k (swapped) + v (normal) projection ----
  // Dk[md][nt]: k̂ᵀ[d][token] ; Dv[vt][dt]: v[token = vt*16+qd*4+rg][d = dt*16+cc]
  v4f Dk[2][4], Dv[4][2];
#pragma unroll
  for (int nt = 0; nt < 4; ++nt) {
    Dk[0][nt] = vzero; Dk[1][nt] = vzero;
    Dv[nt][0] = vzero; Dv[nt][1] = vzero;
  }
  {
    const short* wkb = WkvT + (32 * w + cc) * 256 + qd * 8;
    const short* wvb = WkvT + (256 + 32 * w + cc) * 256 + qd * 8;
#pragma unroll
    for (int it = 0; it < 8; ++it) {
      v8s ak0 = *(const v8s*)(wkb + it * 32);
      v8s ak1 = *(const v8s*)(wkb + 16 * 256 + it * 32);
      v8s bv0 = *(const v8s*)(wvb + it * 32);
      v8s bv1 = *(const v8s*)(wvb + 16 * 256 + it * 32);
#pragma unroll
      for (int nt = 0; nt < 4; ++nt) {
        v8s kf = *(const v8s*)(kvs + (nt * 16 + cc) * 264 + it * 32 + qd * 8);
        Dk[0][nt] = __builtin_amdgcn_mfma_f32_16x16x32_bf16(ak0, kf, Dk[0][nt], 0, 0, 0);
        Dk[1][nt] = __builtin_amdgcn_mfma_f32_16x16x32_bf16(ak1, kf, Dk[1][nt], 0, 0, 0);
        Dv[nt][0] = __builtin_amdgcn_mfma_f32_16x16x32_bf16(kf, bv0, Dv[nt][0], 0, 0, 0);
        Dv[nt][1] = __builtin_amdgcn_mfma_f32_16x16x32_bf16(kf, bv1, Dv[nt][1], 0, 0, 0);
      }
    }
  }
  // k: bias + normalize + xform -> kA (A-frags for Sᵀ)
  v8s kA[4];
  {
    v4f b0 = *(const v4f*)(bkv + 32 * w + qd * 4);
    v4f b1 = *(const v4f*)(bkv + 32 * w + 16 + qd * 4);
#pragma unroll
    for (int nt = 0; nt < 4; ++nt) {
      float s = 0.f;
#pragma unroll
      for (int rg = 0; rg < 4; ++rg) {
        float v0 = Dk[0][nt][rg] + b0[rg];
        float v1 = Dk[1][nt][rg] + b1[rg];
        Dk[0][nt][rg] = v0; Dk[1][nt][rg] = v1;
        s += v0 * v0 + v1 * v1;
      }
      s += __shfl_xor(s, 16); s += __shfl_xor(s, 32);
      float inv = rsqrtf(s + 1e-24f);
      int p00 = packbf(Dk[0][nt][0] * inv, Dk[0][nt][1] * inv);
      int p01 = packbf(Dk[0][nt][2] * inv, Dk[0][nt][3] * inv);
      int p10 = packbf(Dk[1][nt][0] * inv, Dk[1][nt][1] * inv);
      int p11 = packbf(Dk[1][nt][2] * inv, Dk[1][nt][3] * inv);
      kA[nt] = xform_tile(p00, p01, p10, p11, base, mdsel);
    }
  }
  // v: bias + pack + xform -> av[md][kc] (A-frags for PV: A[m=d][k=token])
  v8s av[2][2];
  {
    float bv0 = bkv[256 + 32 * w + cc];
    float bv1 = bkv[256 + 32 * w + 16 + cc];
    int Pv[4][2][2];
#pragma unroll
    for (int vt = 0; vt < 4; ++vt) {
      Pv[vt][0][0] = packbf(Dv[vt][0][0] + bv0, Dv[vt][0][1] + bv0);
      Pv[vt][0][1] = packbf(Dv[vt][0][2] + bv0, Dv[vt][0][3] + bv0);
      Pv[vt][1][0] = packbf(Dv[vt][1][0] + bv1, Dv[vt][1][1] + bv1);
      Pv[vt][1][1] = packbf(Dv[vt][1][2] + bv1, Dv[vt][1][3] + bv1);
    }
#pragma unroll
    for (int md = 0; md < 2; ++md)
#pragma unroll
      for (int kc = 0; kc < 2; ++kc)
        av[md][kc] = xform_tile(Pv[2 * kc][md][0], Pv[2 * kc][md][1],
                                Pv[2 * kc + 1][md][0], Pv[2 * kc + 1][md][1], base, mdsel);
  }

  // ---- phase 3: Sᵀ = k̂ q̂ᵀ (lane holds Sᵀ[j = jt*16+qd*4+rg][i = it*16+cc]) ----
  v4f Sv[4][4];
#pragma unroll
  for (int jt = 0; jt < 4; ++jt)
#pragma unroll
    for (int it = 0; it < 4; ++it)
      Sv[jt][it] = __builtin_amdgcn_mfma_f32_16x16x32_bf16(kA[jt], qB[it], vzero, 0, 0, 0);

  // ---- phase 4: scale/bias/mask + softmax over j (keys) ----
  {
    const float4* itb4 = (const float4*)(itb + (size_t)w * 4096);
    const float4* mw4 = (const float4*)(mask + (size_t)(b & (NWIN - 1)) * 4096);
#pragma unroll
    for (int it = 0; it < 4; ++it) {
      int i = it * 16 + cc;
#pragma unroll
      for (int jt = 0; jt < 4; ++jt) {
        int e = i * 64 + jt * 16 + qd * 4;       // element index (i,j) base, float2 units
        float4 A = itb4[e >> 1];
        float4 B = itb4[(e >> 1) + 1];
        float4 M = mw4[e >> 2];
        Sv[jt][it][0] = Sv[jt][it][0] * A.x + A.y + M.x;
        Sv[jt][it][1] = Sv[jt][it][1] * A.z + A.w + M.y;
        Sv[jt][it][2] = Sv[jt][it][2] * B.x + B.y + M.z;
        Sv[jt][it][3] = Sv[jt][it][3] * B.z + B.w + M.w;
      }
      float mx = -3.4e38f;
#pragma unroll
      for (int jt = 0; jt < 4; ++jt)
#pragma unroll
        for (int rg = 0; rg < 4; ++rg) mx = fmaxf(mx, Sv[jt][it][rg]);
      mx = fmaxf(mx, __shfl_xor(mx, 16)); mx = fmaxf(mx, __shfl_xor(mx, 32));
      float sum = 0.f;
#pragma unroll
      for (int jt = 0; jt < 4; ++jt)
#pragma unroll
        for (int rg = 0; rg < 4; ++rg) {
          float ev = __expf(Sv[jt][it][rg] - mx);
          Sv[jt][it][rg] = ev;
          sum += ev;
        }
      sum += __shfl_xor(sum, 16); sum += __shfl_xor(sum, 32);
      float rs = 1.0f / sum;
#pragma unroll
      for (int jt = 0; jt < 4; ++jt)
#pragma unroll
        for (int rg = 0; rg < 4; ++rg) Sv[jt][it][rg] *= rs;
    }
  }

  // ---- phase 5: P xform + outᵀ = vᵀ Pᵀ ----
  v4f Do[2][4];
  {
#pragma unroll
    for (int it = 0; it < 4; ++it) {
      int pp[4][2];
#pragma unroll
      for (int jt = 0; jt < 4; ++jt) {
        pp[jt][0] = packbf(Sv[jt][it][0], Sv[jt][it][1]);
        pp[jt][1] = packbf(Sv[jt][it][2], Sv[jt][it][3]);
      }
      v8s pB0 = xform_tile(pp[0][0], pp[0][1], pp[1][0], pp[1][1], base, mdsel);
      v8s pB1 = xform_tile(pp[2][0], pp[2][1], pp[3][0], pp[3][1], base, mdsel);
#pragma unroll
      for (int md = 0; md < 2; ++md) {
        v4f t = __builtin_amdgcn_mfma_f32_16x16x32_bf16(av[md][0], pB0, vzero, 0, 0, 0);
        Do[md][it] = __builtin_amdgcn_mfma_f32_16x16x32_bf16(av[md][1], pB1, t, 0, 0, 0);
      }
    }
  }

  // ---- phase 6: gather heads into os[64][264] (@xs region), out = os @ Wp + bp ----
  __syncthreads();   // all waves done reading xs/kvs
#pragma unroll
  for (int md = 0; md < 2; ++md)
#pragma unroll
    for (int it = 0; it < 4; ++it) {
      int addr = (it * 16 + cc) * 264 + 32 * w + md * 16 + qd * 4;
      *(int*)&sm[addr] = packbf(Do[md][it][0], Do[md][it][1]);
      *(int*)&sm[addr + 2] = packbf(Do[md][it][2], Do[md][it][3]);
    }
  __syncthreads();

  v4f pa[4][2];
#pragma unroll
  for (int mt = 0; mt < 4; ++mt) { pa[mt][0] = vzero; pa[mt][1] = vzero; }
  {
    const short* wpb = WpT + (32 * w + cc) * 256 + qd * 8;
#pragma unroll
    for (int it = 0; it < 8; ++it) {
      v8s b0 = *(const v8s*)(wpb + it * 32);
      v8s b1 = *(const v8s*)(wpb + 16 * 256 + it * 32);
#pragma unroll
      for (int mt = 0; mt < 4; ++mt) {
        v8s a = *(const v8s*)(sm + (mt * 16 + cc) * 264 + it * 32 + qd * 8);
        pa[mt][0] = __builtin_amdgcn_mfma_f32_16x16x32_bf16(a, b0, pa[mt][0], 0, 0, 0);
        pa[mt][1] = __builtin_amdgcn_mfma_f32_16x16x32_bf16(a, b1, pa[mt][1], 0, 0, 0);
      }
    }
  }
  {
    float b0 = bp[32 * w + cc], b1 = bp[32 * w + 16 + cc];
    float* ob = out + (size_t)b * 16384;
#pragma unroll
    for (int mt = 0; mt < 4; ++mt)
#pragma unroll
      for (int rg = 0; rg < 4; ++rg) {
        int row = mt * 16 + qd * 4 + rg;
        ob[row * 256 + 32 * w + cc] = pa[mt][0][rg] + b0;
        ob[row * 256 + 32 * w + 16 + cc] = pa[mt][1][rg] + b1;
      }
  }
}

// ---------------- launch ----------------
extern "C" void kernel_launch(void* const* d_in, const int* in_sizes, int n_in,
                              void* d_out, int out_size, void* d_ws, size_t ws_size,
                              hipStream_t stream) {
  const float* x    = (const float*)d_in[0];
  const float* KV   = (const float*)d_in[1];
  const float* mask = (const float*)d_in[2];
  const float* Wq   = (const float*)d_in[3];
  const float* bq   = (const float*)d_in[4];
  const float* Wkv  = (const float*)d_in[5];
  const float* bkv  = (const float*)d_in[6];
  const float* Wp   = (const float*)d_in[7];
  const float* bp   = (const float*)d_in[8];
  const float* cw1  = (const float*)d_in[9];
  const float* cb1  = (const float*)d_in[10];
  const float* cw2  = (const float*)d_in[11];
  const float* cb2  = (const float*)d_in[12];
  const float* tau  = (const float*)d_in[13];
  const float* lri  = (const float*)d_in[14];

  unsigned char* ws = (unsigned char*)d_ws;
  short* WqT   = (short*)(ws + WQT_OFF);
  short* WkvT  = (short*)(ws + WKVT_OFF);
  short* WpT   = (short*)(ws + WPT_OFF);
  float2* itb  = (float2*)(ws + ITB_OFF);

  prep_kernel<<<1152, 256, 0, stream>>>(Wq, Wkv, Wp, tau, WqT, WkvT, WpT, itb);
  cpb_kernel<<<16, 256, 0, stream>>>(cw1, cb1, cw2, cb2, lri, itb);
  wattn_kernel<<<2048, 512, 0, stream>>>(x, KV, mask, bq, bkv, bp,
                                         WqT, WkvT, WpT, itb, (float*)d_out);
}